// Round 6
// baseline (520.417 us; speedup 1.0000x reference)
//
#include <hip/hip_runtime.h>

// ELKUNet forward on MI355X — round 6. f32 device tensors (proven r1/r2/r4/r5).
// Fully fused per-segment design: the only cross-point dependency is the
// within-segment voxel mean (conv uses RAW feats, an input), so 1 wave = 1
// segment does everything:
//   pass 1: enumerate own points from the 2MB bitmap (coords derived from the
//           cell index -> coords[] never read), hash -> pid, feats row load,
//           matvec+LN -> F in LDS, segment sums in REGISTERS.
//   pass 2: vox from registers; per point: neighbor conv (bitmap probe + hash
//           + feats gather, self k=13 included; self row is L1-hot), 2 LNs,
//           relu, out.
// All intermediates (F_input/selfconv/sums/counts/nbr lists) eliminated; no
// atomics on the hot path; ws = 10MB (8MB hash + 2MB bitmap).

typedef unsigned int u32;
typedef unsigned long long u64;

#define EPSV 1e-6f
#define HBITS 20
#define HSIZE (1u << HBITS)
#define HMASK (HSIZE - 1u)
#define CAP 40              // max points per 8^3 segment (Poisson(6.1); P(>=40) ~ 1e-22)

template<int C,int R> __device__ __forceinline__ float dpp_add(float x){
    int y = __builtin_amdgcn_update_dpp(0, __float_as_int(x), C, R, 0xf, true);
    return x + __int_as_float(y);
}
// full 64-lane sum broadcast to all lanes; pure VALU + 1 readlane.
__device__ __forceinline__ float wave_sum(float x){
    x = dpp_add<0xB1,0xF>(x);   // xor 1
    x = dpp_add<0x4E,0xF>(x);   // xor 2
    x = dpp_add<0x141,0xF>(x);  // xor 4
    x = dpp_add<0x140,0xF>(x);  // xor 8
    x = dpp_add<0x142,0xA>(x);  // row_bcast:15
    x = dpp_add<0x143,0xC>(x);  // row_bcast:31
    return __int_as_float(__builtin_amdgcn_readlane(__float_as_int(x), 63));
}

__device__ __forceinline__ u32 hslot(u32 b){ return (b * 0x9E3779B1u) >> (32 - HBITS); }

__global__ void k_scatter(const int* __restrict__ coords, u64* __restrict__ hash,
                          u32* __restrict__ bm, int n){
    int i = blockIdx.x * blockDim.x + threadIdx.x;
    if(i < n){
        int4 c = ((const int4*)coords)[i];
        u32 b = ((u32)c.x << 16) | ((u32)c.y << 8) | (u32)c.z;
        atomicOr(&bm[b >> 5], 1u << (b & 31));
        u64 entry = ((u64)b << 32) | (u32)i;
        u32 s = hslot(b);
        while(atomicCAS(&hash[s], ~0ull, entry) != ~0ull) s = (s + 1) & HMASK;
    }
}

__launch_bounds__(256)
__global__ void k_fused(const float* __restrict__ feats,
                        const float* __restrict__ W_pre,
                        const float* __restrict__ lnpw, const float* __restrict__ lnpb,
                        const float* __restrict__ W_pos, const float* __restrict__ alpha,
                        const float* __restrict__ conv_w,
                        const float* __restrict__ ln_w, const float* __restrict__ ln_b,
                        const float* __restrict__ lnl_w, const float* __restrict__ lnl_b,
                        const u64* __restrict__ hash, const u64* __restrict__ bm64,
                        float* __restrict__ out){
    __shared__ float F_lds[4][CAP][64];
    __shared__ int   pid_lds[4][CAP];
    __shared__ int   cell_lds[4][CAP];

    const int lane = threadIdx.x & 63;
    const int wid  = threadIdx.x >> 6;
    const int seg  = (blockIdx.x << 2) + wid;
    const int cx = seg >> 10, cy = (seg >> 5) & 31, cz = seg & 31;

    // own-segment occupancy: lane covers one (px,py) column of the 8x8x8 cube
    const int pxc = (cx << 3) + (lane >> 3), pyc = (cy << 3) + (lane & 7);
    u64 w = bm64[((size_t)pxc << 10) | ((u32)pyc << 2) | (u32)(cz >> 3)];
    u32 occ8 = (u32)(w >> ((cz & 7) * 8)) & 0xffu;

    u64 m = __ballot(occ8 != 0u);
    if(m == 0ull) return;

    float W[64];   // W_pre[lane][j]
    {   const float4* wr = (const float4*)(W_pre + (size_t)lane * 64);
#pragma unroll
        for(int q = 0; q < 16; ++q){
            float4 v = wr[q];
            W[4*q] = v.x; W[4*q+1] = v.y; W[4*q+2] = v.z; W[4*q+3] = v.w;
        }
    }
    const float wx = W_pos[lane*3+0], wy = W_pos[lane*3+1], wz = W_pos[lane*3+2];
    const float al = alpha[lane];
    const float lpw = lnpw[lane], lpb = lnpb[lane];

    // ---- pass 1: matvec + LN -> LDS; segment sums in registers ----
    int np = 0;
    float aC = 0.f, aS = 0.f, aL = 0.f;
    while(m){
        int l = __ffsll(m) - 1; m &= m - 1;
        u32 o8 = (u32)__builtin_amdgcn_readlane((int)occ8, l);
        int px = (cx << 3) + (l >> 3), py = (cy << 3) + (l & 7);
        while(o8){
            int dz = __ffs(o8) - 1; o8 &= o8 - 1;
            int pz = (cz << 3) + dz;
            u32 b = ((u32)px << 16) | ((u32)py << 8) | (u32)pz;
            u32 s = hslot(b); u64 e;
            while((u32)((e = hash[s]) >> 32) != b) s = (s + 1) & HMASK;
            const int pid = (int)(u32)e;

            const float4* fr = (const float4*)(feats + (size_t)pid * 64);
            float a0=0.f, a1=0.f, a2=0.f, a3=0.f;
#pragma unroll
            for(int q = 0; q < 16; ++q){
                float4 f = fr[q];
                a0 = fmaf(f.x, W[4*q],   a0);
                a1 = fmaf(f.y, W[4*q+1], a1);
                a2 = fmaf(f.z, W[4*q+2], a2);
                a3 = fmaf(f.w, W[4*q+3], a3);
            }
            float acc = (a0 + a1) + (a2 + a3);
            float mn = wave_sum(acc) * (1.f/64.f);
            float t  = acc - mn;
            float v  = wave_sum(t*t) * (1.f/64.f);
            float y  = t * rsqrtf(v + EPSV) * lpw + lpb;

            if(np < CAP){
                F_lds[wid][np][lane] = y;
                if(lane == 0){ pid_lds[wid][np] = pid; cell_lds[wid][np] = (int)b; }
            }
            float pos = ((float)px*wx + (float)py*wy + (float)pz*wz) * al;
            aC = fmaf(y, __cosf(pos), aC);
            aS = fmaf(y, __sinf(pos), aS);
            aL = fmaf(y, pos, aL);
            ++np;
        }
    }

    const float invc = 1.f / (float)(np > 0 ? np : 1);
    const float vC = aC * invc, vS = aS * invc, vL = aL * invc;
    const float lnwv = ln_w[lane], lnbv = ln_b[lane];
    const float llwv = lnl_w[lane], llbv = lnl_b[lane];
    const int npc = np < CAP ? np : CAP;

    // ---- pass 2: vox combine + neighbor conv + LNs + out ----
    for(int p = 0; p < npc; ++p){
        const int pid = pid_lds[wid][p];
        const u32 b   = (u32)cell_lds[wid][p];
        const int px = (int)(b >> 16), py = (int)((b >> 8) & 255u), pz = (int)(b & 255u);

        float F = F_lds[wid][p][lane];
        float pos = ((float)px*wx + (float)py*wy + (float)pz*wz) * al;
        float sn = __sinf(pos), cs = __cosf(pos);
        float newF = fmaf(vC, cs, fmaf(vS, sn, vL - F*pos));

        // neighbor probe: lanes 0..8 cover (dx,dy); 3 z-bits each (self kept)
        u32 m3 = 0;
        if(lane < 9){
            int nx = px + lane/3 - 1, ny = py + lane%3 - 1;
            if(((u32)nx < 256u) && ((u32)ny < 256u)){
                const u64* wp = bm64 + (((size_t)nx << 10) | ((u32)ny << 2));
                int zb = pz & 63;
                if(zb >= 1 && zb <= 62){
                    u64 ww = wp[pz >> 6];
                    m3 = (u32)((ww >> (zb - 1)) & 7ull);
                } else {
#pragma unroll
                    for(int t = 0; t < 3; ++t){
                        int zz = pz + t - 1;
                        if((u32)zz < 256u){
                            u64 ww = wp[zz >> 6];
                            m3 |= (u32)((ww >> (zz & 63)) & 1ull) << t;
                        }
                    }
                }
            }
        }
        u64 b0 = __ballot(m3 & 1u);
        u64 b1 = __ballot(m3 & 2u);
        u64 b2 = __ballot(m3 & 4u);

        float local = 0.f;
#pragma unroll
        for(int t = 0; t < 3; ++t){
            u64 mm = (t == 0) ? b0 : ((t == 1) ? b1 : b2);
            while(mm){
                int l2 = __ffsll(mm) - 1; mm &= mm - 1;
                int nx = px + l2/3 - 1, ny = py + l2%3 - 1, nz = pz + t - 1;
                int k = 3*l2 + t;
                u32 nb = ((u32)nx << 16) | ((u32)ny << 8) | (u32)nz;
                u32 s = hslot(nb); u64 e;
                while((u32)((e = hash[s]) >> 32) != nb) s = (s + 1) & HMASK;
                const int pin = (int)(u32)e;

                const float4* gv = (const float4*)(feats + (size_t)pin * 64);
                const float* cw = conv_w + (size_t)k * 4096;
#pragma unroll
                for(int q = 0; q < 16; ++q){
                    float4 g = gv[q];
                    local = fmaf(g.x, cw[(4*q    )*64 + lane], local);
                    local = fmaf(g.y, cw[(4*q + 1)*64 + lane], local);
                    local = fmaf(g.z, cw[(4*q + 2)*64 + lane], local);
                    local = fmaf(g.w, cw[(4*q + 3)*64 + lane], local);
                }
            }
        }

        float m1 = wave_sum(newF) * (1.f/64.f);
        float t1 = newF - m1;
        float v1 = wave_sum(t1*t1) * (1.f/64.f);
        float o1 = t1 * rsqrtf(v1 + EPSV) * lnwv + lnbv;

        float m2 = wave_sum(local) * (1.f/64.f);
        float t2 = local - m2;
        float v2 = wave_sum(t2*t2) * (1.f/64.f);
        float o2 = t2 * rsqrtf(v2 + EPSV) * llwv + llbv;

        out[(size_t)pid*64 + lane] = fmaxf(o1 + o2, 0.f);
    }
}

extern "C" void kernel_launch(void* const* d_in, const int* in_sizes, int n_in,
                              void* d_out, int out_size, void* d_ws, size_t ws_size,
                              hipStream_t stream) {
    (void)n_in; (void)out_size; (void)ws_size;
    const float* feats    = (const float*)d_in[0];
    const float* W_pre    = (const float*)d_in[1];
    const float* ln_pre_w = (const float*)d_in[2];
    const float* ln_pre_b = (const float*)d_in[3];
    const float* W_pos    = (const float*)d_in[4];
    const float* alpha    = (const float*)d_in[5];
    const float* conv_w   = (const float*)d_in[6];
    const float* ln_w     = (const float*)d_in[7];
    const float* ln_b     = (const float*)d_in[8];
    const float* lnl_w    = (const float*)d_in[9];
    const float* lnl_b    = (const float*)d_in[10];
    const int*   coords   = (const int*)d_in[11];

    const int n = in_sizes[0] / 64;

    char* ws = (char*)d_ws;
    u64* hash = (u64*)ws;                 // 8,388,608 B
    u32* bm   = (u32*)(ws + 8388608);     // 2,097,152 B
    u64* bm64 = (u64*)(ws + 8388608);

    hipMemsetAsync(hash, 0xFF, 8388608, stream);
    hipMemsetAsync(bm, 0, 2097152, stream);

    k_scatter<<<(n + 255)/256, 256, 0, stream>>>(coords, hash, bm, n);
    k_fused<<<8192, 256, 0, stream>>>(feats, W_pre, ln_pre_w, ln_pre_b,
                                      W_pos, alpha, conv_w,
                                      ln_w, ln_b, lnl_w, lnl_b,
                                      hash, bm64, (float*)d_out);
}

// Round 7
// 322.463 us; speedup vs baseline: 1.6139x; 1.6139x over previous
//
#include <hip/hip_runtime.h>

// ELKUNet forward on MI355X — round 7. f32 device tensors (proven r1/r2/r4/r5).
// Lesson r6: segment-fused = latency-bound (serial per-point chains, 3 waves/
// SIMD). Recombine proven point-parallel kernels (r5) with an atomic-free
// segment-sum gather:
//   k_scatter: bitmap + cell->pid hash
//   k_nbr:     per-(pt,dir) lane-parallel neighbor lists
//   k_pre:     matvec+LN -> F_input, selfconv (NO atomics; r4's version)
//   k_seg:     1 wave/segment; 1 bm64 load = all 512 cells; LANE-PARALLEL hash
//              probes; ~6 F-row accumulations per wave. No atomics.
//   k_final:   r5's software-pipelined per-point finale (verbatim).

typedef unsigned int u32;
typedef unsigned long long u64;

#define EPSV 1e-6f
#define HBITS 20
#define HSIZE (1u << HBITS)
#define HMASK (HSIZE - 1u)

template<int C,int R> __device__ __forceinline__ float dpp_add(float x){
    int y = __builtin_amdgcn_update_dpp(0, __float_as_int(x), C, R, 0xf, true);
    return x + __int_as_float(y);
}
// full 64-lane sum broadcast to all lanes; pure VALU + 1 readlane.
__device__ __forceinline__ float wave_sum(float x){
    x = dpp_add<0xB1,0xF>(x);   // xor 1
    x = dpp_add<0x4E,0xF>(x);   // xor 2
    x = dpp_add<0x141,0xF>(x);  // xor 4
    x = dpp_add<0x140,0xF>(x);  // xor 8
    x = dpp_add<0x142,0xA>(x);  // row_bcast:15
    x = dpp_add<0x143,0xC>(x);  // row_bcast:31
    return __int_as_float(__builtin_amdgcn_readlane(__float_as_int(x), 63));
}

__device__ __forceinline__ u32 hslot(u32 b){ return (b * 0x9E3779B1u) >> (32 - HBITS); }

__global__ void k_scatter(const int* __restrict__ coords, u64* __restrict__ hash,
                          u32* __restrict__ bm, int n){
    int i = blockIdx.x * blockDim.x + threadIdx.x;
    if(i < n){
        int4 c = ((const int4*)coords)[i];
        u32 b = ((u32)c.x << 16) | ((u32)c.y << 8) | (u32)c.z;
        atomicOr(&bm[b >> 5], 1u << (b & 31));
        u64 entry = ((u64)b << 32) | (u32)i;
        u32 s = hslot(b);
        while(atomicCAS(&hash[s], ~0ull, entry) != ~0ull) s = (s + 1) & HMASK;
    }
}

// 1 thread per (point, direction): bitmap probe -> hash lookup -> append list.
__global__ void k_nbr(const int* __restrict__ coords, const u64* __restrict__ hash,
                      const u32* __restrict__ bm, u32* __restrict__ nbrcnt,
                      u32* __restrict__ nbrlst, int n){
    int t = blockIdx.x * blockDim.x + threadIdx.x;
    int pt = t / 27;
    if(pt >= n) return;
    int d = t - pt * 27;
    if(d == 13) return;                          // self handled densely in k_pre
    int4 c = ((const int4*)coords)[pt];
    int nx = c.x + d / 9 - 1, ny = c.y + (d / 3) % 3 - 1, nz = c.z + d % 3 - 1;
    if(((u32)nx >= 256u) | ((u32)ny >= 256u) | ((u32)nz >= 256u)) return;
    u32 b = ((u32)nx << 16) | ((u32)ny << 8) | (u32)nz;
    if(!((bm[b >> 5] >> (b & 31)) & 1u)) return;
    u32 s = hslot(b);
    u64 e;
    while((u32)((e = hash[s]) >> 32) != b) s = (s + 1) & HMASK;
    u32 slot = atomicAdd(&nbrcnt[pt], 1u);
    if(slot < 8u) nbrlst[(size_t)pt * 8 + slot] = ((u32)d << 25) | (u32)e;
}

// F_input = LN(feats @ W_pre^T); selfconv = feats @ conv_w[13]. No atomics.
__launch_bounds__(256)
__global__ void k_pre(const float* __restrict__ feats, const float* __restrict__ W_pre,
                      const float* __restrict__ lnw, const float* __restrict__ lnb,
                      const float* __restrict__ conv_w,
                      float* __restrict__ F_input, float* __restrict__ selfconv,
                      int n, int nwaves){
    const int lane = threadIdx.x & 63;
    const int wave = (blockIdx.x * blockDim.x + threadIdx.x) >> 6;

    float W[64];   // W_pre[lane][j]
    {   const float4* wr = (const float4*)(W_pre + (size_t)lane * 64);
#pragma unroll
        for(int q = 0; q < 16; ++q){
            float4 v = wr[q];
            W[4*q] = v.x; W[4*q+1] = v.y; W[4*q+2] = v.z; W[4*q+3] = v.w;
        }
    }
    float W13[64]; // conv_w[13][j][lane]
#pragma unroll
    for(int j = 0; j < 64; ++j) W13[j] = conv_w[(13*64 + j)*64 + lane];

    const float lw = lnw[lane], lb = lnb[lane];

    for(int i = wave; i < n; i += nwaves){
        const int si = __builtin_amdgcn_readfirstlane(i);
        const float4* fr = (const float4*)(feats + (size_t)si * 64);
        float a0=0.f, a1=0.f, a2=0.f, a3=0.f;
        float s0=0.f, s1=0.f, s2=0.f, s3=0.f;
#pragma unroll
        for(int q = 0; q < 16; ++q){
            float4 f = fr[q];
            a0 = fmaf(f.x, W[4*q],   a0);
            a1 = fmaf(f.y, W[4*q+1], a1);
            a2 = fmaf(f.z, W[4*q+2], a2);
            a3 = fmaf(f.w, W[4*q+3], a3);
            s0 = fmaf(f.x, W13[4*q],   s0);
            s1 = fmaf(f.y, W13[4*q+1], s1);
            s2 = fmaf(f.z, W13[4*q+2], s2);
            s3 = fmaf(f.w, W13[4*q+3], s3);
        }
        float acc = (a0 + a1) + (a2 + a3);
        float m = wave_sum(acc) * (1.f/64.f);
        float t = acc - m;
        float v = wave_sum(t*t) * (1.f/64.f);
        F_input[(size_t)si*64 + lane] = t * rsqrtf(v + EPSV) * lw + lb;
        selfconv[(size_t)si*64 + lane] = (s0 + s1) + (s2 + s3);
    }
}

// Segment sums: 1 wave = 1 segment; lane-parallel hash probes; no atomics.
__launch_bounds__(256)
__global__ void k_seg(const float* __restrict__ F_input, const u64* __restrict__ hash,
                      const u64* __restrict__ bm64, const float* __restrict__ W_pos,
                      const float* __restrict__ alpha,
                      float* __restrict__ sums, float* __restrict__ counts){
    const int lane = threadIdx.x & 63;
    const int seg  = (blockIdx.x << 2) + (threadIdx.x >> 6);
    const int cx = seg >> 10, cy = (seg >> 5) & 31, cz = seg & 31;

    // lane -> one (px,py) column; its 8 z-cells come from one bm64 load
    const int px = (cx << 3) + (lane >> 3), py = (cy << 3) + (lane & 7);
    u64 w = bm64[((size_t)px << 10) | ((u32)py << 2) | (u32)(cz >> 3)];
    u32 o8 = (u32)(w >> ((cz & 7) * 8)) & 0xffu;
    float cnt = wave_sum((float)__popc(o8));

    const float wx = W_pos[lane*3+0], wy = W_pos[lane*3+1], wz = W_pos[lane*3+2];
    const float al = alpha[lane];

    float aC = 0.f, aS = 0.f, aL = 0.f;
    while(__ballot(o8 != 0u)){
        int myz = 0, pid = -1;
        if(o8){
            int dz = __ffs(o8) - 1; o8 &= o8 - 1;
            myz = (cz << 3) + dz;
            u32 b = ((u32)px << 16) | ((u32)py << 8) | (u32)myz;
            u32 s = hslot(b); u64 e;
            while((u32)((e = hash[s]) >> 32) != b) s = (s + 1) & HMASK;   // lane-parallel
            pid = (int)(u32)e;
        }
        u64 mm = __ballot(pid >= 0);
        while(mm){
            int l = __ffsll(mm) - 1; mm &= mm - 1;
            int p  = __builtin_amdgcn_readlane(pid, l);
            int pz = __builtin_amdgcn_readlane(myz, l);
            int qx = (cx << 3) + (l >> 3), qy = (cy << 3) + (l & 7);
            float F = F_input[(size_t)p * 64 + lane];
            float pos = ((float)qx*wx + (float)qy*wy + (float)pz*wz) * al;
            aC = fmaf(F, __cosf(pos), aC);
            aS = fmaf(F, __sinf(pos), aS);
            aL = fmaf(F, pos, aL);
        }
    }
    float* sp = sums + (size_t)seg * 192;
    sp[lane] = aC; sp[64 + lane] = aS; sp[128 + lane] = aL;
    if(lane == 0) counts[seg] = cnt;
}

// Software-pipelined final: prefetch point i+1's loads while computing point i.
__launch_bounds__(256)
__global__ void k_final(const float* __restrict__ feats,
                        const float* __restrict__ F_input,
                        const float* __restrict__ selfconv,
                        const float* __restrict__ W_pos, const float* __restrict__ alpha,
                        const float* __restrict__ conv_w,
                        const float* __restrict__ ln_w, const float* __restrict__ ln_b,
                        const float* __restrict__ lnl_w, const float* __restrict__ lnl_b,
                        const int* __restrict__ coords,
                        const float* __restrict__ sums, const float* __restrict__ counts,
                        const u32* __restrict__ nbrcnt, const u32* __restrict__ nbrlst,
                        float* __restrict__ out, int n, int nwaves){
    const int lane = threadIdx.x & 63;
    const int wave = (blockIdx.x * blockDim.x + threadIdx.x) >> 6;

    const float wx = W_pos[lane*3+0], wy = W_pos[lane*3+1], wz = W_pos[lane*3+2];
    const float al = alpha[lane];
    const float lnwv = ln_w[lane], lnbv = ln_b[lane];
    const float llwv = lnl_w[lane], llbv = lnl_b[lane];

    int i = wave;
    if(i >= n) return;

    int siA = __builtin_amdgcn_readfirstlane(i);
    int4 cA = ((const int4*)coords)[siA];
    int segA = ((cA.x >> 3) << 10) | ((cA.y >> 3) << 5) | (cA.z >> 3);
    const float* spA = sums + (size_t)segA * 192;
    float s0A = spA[lane], s1A = spA[64+lane], s2A = spA[128+lane];
    float cntA = counts[segA];
    float FA = F_input[(size_t)siA*64 + lane];
    float ScA = selfconv[(size_t)siA*64 + lane];
    u32 ncA = nbrcnt[siA];
    u32 e0A = nbrlst[(size_t)siA*8];

    for(; i < n; ){
        const int inext = i + nwaves;
        const bool hB = inext < n;
        int siB = 0; int4 cB = cA; float s0B=0,s1B=0,s2B=0,cntB=0,FB=0,ScB=0;
        u32 ncB = 0, e0B = 0;
        if(hB){
            siB = __builtin_amdgcn_readfirstlane(inext);
            cB = ((const int4*)coords)[siB];
            int segB = ((cB.x >> 3) << 10) | ((cB.y >> 3) << 5) | (cB.z >> 3);
            const float* spB = sums + (size_t)segB * 192;
            s0B = spB[lane]; s1B = spB[64+lane]; s2B = spB[128+lane];
            cntB = counts[segB];
            FB = F_input[(size_t)siB*64 + lane];
            ScB = selfconv[(size_t)siB*64 + lane];
            ncB = nbrcnt[siB];
            e0B = nbrlst[(size_t)siB*8];
        }

        // ---- compute A ----
        float pos = ((float)cA.x*wx + (float)cA.y*wy + (float)cA.z*wz) * al;
        float sn = __sinf(pos), cs = __cosf(pos);
        float inv = 1.f / fmaxf(cntA, 1.f);
        float newF = fmaf(s0A*inv, cs, fmaf(s1A*inv, sn, s2A*inv - FA*pos));
        float local = ScA;

        u32 cc = ncA > 8u ? 8u : ncA;
        if(cc){
            u32 e = e0A;
            u32 c2 = 0;
            for(;;){
                u32 k = e >> 25, pi = e & 0x1FFFFFFu;
                const float4* gv = (const float4*)(feats + (size_t)pi * 64);
                const float* cw = conv_w + (size_t)k * 4096;
#pragma unroll
                for(int q = 0; q < 16; ++q){
                    float4 g = gv[q];
                    local = fmaf(g.x, cw[(4*q    )*64 + lane], local);
                    local = fmaf(g.y, cw[(4*q + 1)*64 + lane], local);
                    local = fmaf(g.z, cw[(4*q + 2)*64 + lane], local);
                    local = fmaf(g.w, cw[(4*q + 3)*64 + lane], local);
                }
                if(++c2 >= cc) break;
                e = nbrlst[(size_t)siA*8 + c2];
            }
        }

        float m1 = wave_sum(newF) * (1.f/64.f);
        float t1 = newF - m1;
        float v1 = wave_sum(t1*t1) * (1.f/64.f);
        float a1 = t1 * rsqrtf(v1 + EPSV) * lnwv + lnbv;

        float m2 = wave_sum(local) * (1.f/64.f);
        float t2 = local - m2;
        float v2 = wave_sum(t2*t2) * (1.f/64.f);
        float a2 = t2 * rsqrtf(v2 + EPSV) * llwv + llbv;

        out[(size_t)siA*64 + lane] = fmaxf(a1 + a2, 0.f);

        i = inext;
        if(hB){
            siA = siB; cA = cB;
            s0A = s0B; s1A = s1B; s2A = s2B; cntA = cntB;
            FA = FB; ScA = ScB; ncA = ncB; e0A = e0B;
        }
    }
}

extern "C" void kernel_launch(void* const* d_in, const int* in_sizes, int n_in,
                              void* d_out, int out_size, void* d_ws, size_t ws_size,
                              hipStream_t stream) {
    (void)n_in; (void)out_size; (void)ws_size;
    const float* feats    = (const float*)d_in[0];
    const float* W_pre    = (const float*)d_in[1];
    const float* ln_pre_w = (const float*)d_in[2];
    const float* ln_pre_b = (const float*)d_in[3];
    const float* W_pos    = (const float*)d_in[4];
    const float* alpha    = (const float*)d_in[5];
    const float* conv_w   = (const float*)d_in[6];
    const float* ln_w     = (const float*)d_in[7];
    const float* ln_b     = (const float*)d_in[8];
    const float* lnl_w    = (const float*)d_in[9];
    const float* lnl_b    = (const float*)d_in[10];
    const int*   coords   = (const int*)d_in[11];

    const int n = in_sizes[0] / 64;

    char* ws = (char*)d_ws;
    size_t o = 0;
    u64*   hash    = (u64*)(ws + o);   o += (size_t)HSIZE * 8;          // 8,388,608
    size_t zoff    = o;
    u32*   bm      = (u32*)(ws + o);   o += 2097152;                    // 2MB bitmap
    u64*   bm64    = (u64*)bm;
    u32*   nbrcnt  = (u32*)(ws + o);   o += ((size_t)n*4 + 255) & ~(size_t)255;
    size_t zspan   = o - zoff;
    float* sums    = (float*)(ws + o); o += 25165824;                   // written by k_seg (no memset)
    float* counts  = (float*)(ws + o); o += 131072;                     // written by k_seg
    u32*   nbrlst  = (u32*)(ws + o);   o += (size_t)n * 32;             // 8 slots/pt
    float* F_input = (float*)(ws + o); o += (size_t)n * 256;
    float* selfconv= (float*)(ws + o); o += (size_t)n * 256;
    // total ~145.4MB <= proven available (r2/r4/r5)

    hipMemsetAsync(hash, 0xFF, (size_t)HSIZE * 8, stream);
    hipMemsetAsync(ws + zoff, 0, zspan, stream);

    k_scatter<<<(n + 255)/256, 256, 0, stream>>>(coords, hash, bm, n);
    k_nbr<<<(n*27 + 255)/256, 256, 0, stream>>>(coords, hash, bm, nbrcnt, nbrlst, n);
    k_pre<<<2048, 256, 0, stream>>>(feats, W_pre, ln_pre_w, ln_pre_b, conv_w,
                                    F_input, selfconv, n, 8192);
    k_seg<<<8192, 256, 0, stream>>>(F_input, hash, bm64, W_pos, alpha, sums, counts);
    k_final<<<2048, 256, 0, stream>>>(feats, F_input, selfconv, W_pos, alpha, conv_w,
                                      ln_w, ln_b, lnl_w, lnl_b, coords,
                                      sums, counts, nbrcnt, nbrlst,
                                      (float*)d_out, n, 8192);
}